// Round 6
// baseline (364.240 us; speedup 1.0000x reference)
//
#include <hip/hip_runtime.h>
#include <hip/hip_bf16.h>

typedef __attribute__((ext_vector_type(8))) short bf16x8;
typedef __attribute__((ext_vector_type(4))) float f32x4;

#define DH 128
#define DOUT 64

static __device__ __forceinline__ unsigned short f2bf(float f) {
    __hip_bfloat16 h = __float2bfloat16(f);
    return *(unsigned short*)&h;
}
static __device__ __forceinline__ void acc2(float& a0, float& a1, unsigned int u) {
    a0 += __uint_as_float(u << 16);
    a1 += __uint_as_float(u & 0xffff0000u);
}

// ---------------- prep: x -> bf16, weights -> bf16 transposed [n][k], zero cnt ----------------

struct WPrep {
    const float* src[8];
    unsigned short* dst[8];
};

__global__ void prep_kernel(const float* __restrict__ x, unsigned short* __restrict__ xb,
                            int n4, WPrep p, int* __restrict__ cnt, int N_) {
    int id = blockIdx.x * blockDim.x + threadIdx.x;
    if (id < n4) {
        float4 v = ((const float4*)x)[id];
        ushort4 b;
        b.x = f2bf(v.x); b.y = f2bf(v.y); b.z = f2bf(v.z); b.w = f2bf(v.w);
        ((ushort4*)xb)[id] = b;
        return;
    }
    id -= n4;
    if (id < N_) { cnt[id] = 0; return; }
    id -= N_;
    int m, off;
    if (id < 7 * 16384) { m = id >> 14; off = id & 16383; }
    else {
        m = 7; off = id - 7 * 16384;
        if (off >= 8192) return;
    }
    int shift = (m == 7) ? 6 : 7;
    int nc = 1 << shift;
    int k = off >> shift;
    int n = off & (nc - 1);
    p.dst[m][n * 128 + k] = f2bf(p.src[m][off]);
}

// ---------------- CSR build ----------------

__global__ void hist_kernel(const int* __restrict__ dst, int* __restrict__ cnt,
                            int* __restrict__ rank, int E, int n) {
    int e = blockIdx.x * blockDim.x + threadIdx.x;
    if (e < E) {
        int d = dst[e];
        if ((unsigned)d < (unsigned)n) rank[e] = atomicAdd(&cnt[d], 1);
    }
}

__global__ void scan1_kernel(const int* __restrict__ cnt, int* __restrict__ rp_part,
                             int* __restrict__ bsum, int n) {
    __shared__ int s[256];
    int tid = threadIdx.x;
    int i = blockIdx.x * 256 + tid;
    int v = (i < n) ? cnt[i] : 0;
    s[tid] = v;
    __syncthreads();
    for (int off = 1; off < 256; off <<= 1) {
        int t = (tid >= off) ? s[tid - off] : 0;
        __syncthreads();
        s[tid] += t;
        __syncthreads();
    }
    if (i < n) rp_part[i] = s[tid] - v;
    if (tid == 255) bsum[blockIdx.x] = s[255];
}

__global__ void scan2_kernel(int* __restrict__ bsum, int nb) {
    __shared__ int s[256];
    int tid = threadIdx.x;
    int v = (tid < nb) ? bsum[tid] : 0;
    s[tid] = v;
    __syncthreads();
    for (int off = 1; off < 256; off <<= 1) {
        int t = (tid >= off) ? s[tid - off] : 0;
        __syncthreads();
        s[tid] += t;
        __syncthreads();
    }
    if (tid < nb) bsum[tid] = s[tid] - v;
}

// final row_ptr + atomic-free edge fill in one pass (both depend only on scan1+scan2)
__global__ void scan3_fill_kernel(const int* __restrict__ rp_part, const int* __restrict__ bsum,
                                  int* __restrict__ row_ptr,
                                  const int* __restrict__ src, const int* __restrict__ dst,
                                  const int* __restrict__ rank, int* __restrict__ esrc,
                                  int n, int E) {
    int gid = blockIdx.x * blockDim.x + threadIdx.x;
    if (gid < n) row_ptr[gid] = rp_part[gid] + bsum[gid >> 8];
    else if (gid == n) row_ptr[n] = E;
    if (gid < E) {
        int d = dst[gid];
        if ((unsigned)d < (unsigned)n)
            esrc[rp_part[d] + bsum[d >> 8] + rank[gid]] = src[gid];
    }
}

// ---------------- fused layer: agg -> GEMM1(relu) -> GEMM2 [-> GEMM3(relu) -> GEMM4] ----------------
// 16-row M tile, 256 threads (4 waves), grid = N/16.
// Gather: lane covers 16B chunk (lane&15) of edge-slot (lane>>4); one dwordx4 = 4 edges;
// 4 nodes interleaved per wave -> up to 16KB in flight. Cross-group sum via shfl_xor.
// Weights bf16-transposed in global (L1/L2-resident). LDS 8.7 KB.

template <bool HEAD>
__launch_bounds__(256, 6)
__global__ void layer_kernel(const unsigned short* __restrict__ h,
                             const int* __restrict__ row_ptr,
                             const int* __restrict__ esrc,
                             const unsigned short* __restrict__ W1t,
                             const float* __restrict__ b1,
                             const unsigned short* __restrict__ W2t,
                             const float* __restrict__ b2,
                             const unsigned short* __restrict__ W3t,
                             const float* __restrict__ b3,
                             const unsigned short* __restrict__ W4t,
                             const float* __restrict__ b4,
                             void* __restrict__ outp, int M) {
    constexpr int LDA = 128 + 8;
    __shared__ __align__(16) unsigned short As[16][LDA];
    __shared__ __align__(16) unsigned short Zs[16][LDA];

    int tid = threadIdx.x;
    int wave = __builtin_amdgcn_readfirstlane(tid >> 6);
    int lane = tid & 63;
    int grp = lane >> 4;   // edge-slot group 0..3
    int c = lane & 15;     // 16B chunk of a 256B row
    int row0 = blockIdx.x * 16;
    int nodes0 = row0 + wave * 4;

    // ---- gather phase: 4 nodes per wave, interleaved ----
    int b[4], e[4];
#pragma unroll
    for (int i = 0; i < 4; ++i) {
        int nd = nodes0 + i;
        b[i] = (nd < M) ? row_ptr[nd] : 0;
        e[i] = (nd < M) ? row_ptr[nd + 1] : 0;
    }
    float acc[4][8];
#pragma unroll
    for (int i = 0; i < 4; ++i)
#pragma unroll
        for (int j = 0; j < 8; ++j) acc[i][j] = 0.f;

    int pos[4];
#pragma unroll
    for (int i = 0; i < 4; ++i) pos[i] = b[i] + grp;
    int itmax = 0;
#pragma unroll
    for (int i = 0; i < 4; ++i) {
        int it = (e[i] - b[i] + 3) >> 2;
        itmax = it > itmax ? it : itmax;
    }

    for (int it = 0; it < itmax; ++it) {
        int idx[4] = {0, 0, 0, 0};
#pragma unroll
        for (int i = 0; i < 4; ++i)
            if (pos[i] < e[i]) idx[i] = esrc[pos[i]];
        uint4 u[4];
#pragma unroll
        for (int i = 0; i < 4; ++i) u[i] = make_uint4(0u, 0u, 0u, 0u);
#pragma unroll
        for (int i = 0; i < 4; ++i)
            if (pos[i] < e[i])
                u[i] = *((const uint4*)((const char*)h + ((size_t)idx[i] << 8)) + c);
#pragma unroll
        for (int i = 0; i < 4; ++i) {
            acc2(acc[i][0], acc[i][1], u[i].x);
            acc2(acc[i][2], acc[i][3], u[i].y);
            acc2(acc[i][4], acc[i][5], u[i].z);
            acc2(acc[i][6], acc[i][7], u[i].w);
            pos[i] += 4;
        }
    }

    // reduce across the 4 edge-slot groups, add self, write As
#pragma unroll
    for (int i = 0; i < 4; ++i) {
        int nd = nodes0 + i;
#pragma unroll
        for (int j = 0; j < 8; ++j) {
            float v = acc[i][j];
            v += __shfl_xor(v, 16, 64);
            v += __shfl_xor(v, 32, 64);
            acc[i][j] = v;
        }
        if (nd < M) {
            uint4 s = *((const uint4*)((const char*)h + ((size_t)nd << 8)) + c);
            acc2(acc[i][0], acc[i][1], s.x);
            acc2(acc[i][2], acc[i][3], s.y);
            acc2(acc[i][4], acc[i][5], s.z);
            acc2(acc[i][6], acc[i][7], s.w);
        }
        if (grp == 0) {
            uint4 ov;
            ov.x = (unsigned)f2bf(acc[i][0]) | ((unsigned)f2bf(acc[i][1]) << 16);
            ov.y = (unsigned)f2bf(acc[i][2]) | ((unsigned)f2bf(acc[i][3]) << 16);
            ov.z = (unsigned)f2bf(acc[i][4]) | ((unsigned)f2bf(acc[i][5]) << 16);
            ov.w = (unsigned)f2bf(acc[i][6]) | ((unsigned)f2bf(acc[i][7]) << 16);
            *(uint4*)(&As[wave * 4 + i][c * 8]) = ov;
        }
    }
    __syncthreads();

    int quad = lane >> 4;
    int l16 = lane & 15;

    // ---- GEMM1: Zs = relu(As @ W1 + b1) ----
    bf16x8 af[4];
#pragma unroll
    for (int kt = 0; kt < 4; ++kt)
        af[kt] = *(const bf16x8*)(&As[l16][kt * 32 + quad * 8]);
#pragma unroll
    for (int p = 0; p < 2; ++p) {
        int ncol = (wave * 2 + p) * 16 + l16;
        const unsigned short* wp = W1t + ncol * 128 + quad * 8;
        f32x4 a = {0.f, 0.f, 0.f, 0.f};
#pragma unroll
        for (int kt = 0; kt < 4; ++kt)
            a = __builtin_amdgcn_mfma_f32_16x16x32_bf16(
                af[kt], *(const bf16x8*)(wp + kt * 32), a, 0, 0, 0);
        float bs = b1[ncol];
#pragma unroll
        for (int r = 0; r < 4; ++r) {
            float v = a[r] + bs;
            if (v < 0.f) v = 0.f;
            Zs[quad * 4 + r][ncol] = f2bf(v);
        }
    }
    __syncthreads();

    // ---- GEMM2: relu(Zs @ W2 + b2) -> global bf16 (conv) or As (head path) ----
    bf16x8 zf[4];
#pragma unroll
    for (int kt = 0; kt < 4; ++kt)
        zf[kt] = *(const bf16x8*)(&Zs[l16][kt * 32 + quad * 8]);
#pragma unroll
    for (int p = 0; p < 2; ++p) {
        int ncol = (wave * 2 + p) * 16 + l16;
        const unsigned short* wp = W2t + ncol * 128 + quad * 8;
        f32x4 a = {0.f, 0.f, 0.f, 0.f};
#pragma unroll
        for (int kt = 0; kt < 4; ++kt)
            a = __builtin_amdgcn_mfma_f32_16x16x32_bf16(
                zf[kt], *(const bf16x8*)(wp + kt * 32), a, 0, 0, 0);
        float bs = b2[ncol];
#pragma unroll
        for (int r = 0; r < 4; ++r) {
            float v = a[r] + bs;
            if (v < 0.f) v = 0.f;
            if (HEAD) {
                As[quad * 4 + r][ncol] = f2bf(v);
            } else {
                int grow = row0 + quad * 4 + r;
                if (grow < M)
                    ((unsigned short*)outp)[(size_t)grow * 128 + ncol] = f2bf(v);
            }
        }
    }

    if (HEAD) {
        __syncthreads();
        // ---- GEMM3: Zs = relu(As @ W3 + b3) ----
        bf16x8 hf[4];
#pragma unroll
        for (int kt = 0; kt < 4; ++kt)
            hf[kt] = *(const bf16x8*)(&As[l16][kt * 32 + quad * 8]);
#pragma unroll
        for (int p = 0; p < 2; ++p) {
            int ncol = (wave * 2 + p) * 16 + l16;
            const unsigned short* wp = W3t + ncol * 128 + quad * 8;
            f32x4 a = {0.f, 0.f, 0.f, 0.f};
#pragma unroll
            for (int kt = 0; kt < 4; ++kt)
                a = __builtin_amdgcn_mfma_f32_16x16x32_bf16(
                    hf[kt], *(const bf16x8*)(wp + kt * 32), a, 0, 0, 0);
            float bs = b3[ncol];
#pragma unroll
            for (int r = 0; r < 4; ++r) {
                float v = a[r] + bs;
                if (v < 0.f) v = 0.f;
                Zs[quad * 4 + r][ncol] = f2bf(v);
            }
        }
        __syncthreads();
        // ---- GEMM4: d_out = Zs @ W4 + b4 (fp32, 64 cols) ----
        bf16x8 gf[4];
#pragma unroll
        for (int kt = 0; kt < 4; ++kt)
            gf[kt] = *(const bf16x8*)(&Zs[l16][kt * 32 + quad * 8]);
        {
            int ncol = wave * 16 + l16;
            const unsigned short* wp = W4t + ncol * 128 + quad * 8;
            f32x4 a = {0.f, 0.f, 0.f, 0.f};
#pragma unroll
            for (int kt = 0; kt < 4; ++kt)
                a = __builtin_amdgcn_mfma_f32_16x16x32_bf16(
                    gf[kt], *(const bf16x8*)(wp + kt * 32), a, 0, 0, 0);
            float bs = b4[ncol];
#pragma unroll
            for (int r = 0; r < 4; ++r) {
                int grow = row0 + quad * 4 + r;
                if (grow < M)
                    ((float*)outp)[(size_t)grow * 64 + ncol] = a[r] + bs;
            }
        }
    }
}

// ---------------- launch ----------------

extern "C" void kernel_launch(void* const* d_in, const int* in_sizes, int n_in,
                              void* d_out, int out_size, void* d_ws, size_t ws_size,
                              hipStream_t stream) {
    const float* x = (const float*)d_in[0];
    const int* ei = (const int*)d_in[1];
    int N = in_sizes[0] / DH;
    int E = in_sizes[1] / 2;
    const int* src = ei;
    const int* dstv = ei + E;

    char* ws = (char*)d_ws;
    size_t off = 0;
    auto alloc = [&](size_t bytes) -> void* {
        void* p = ws + off;
        off += (bytes + 255) & ~(size_t)255;
        return p;
    };
    unsigned short* xb = (unsigned short*)alloc((size_t)N * DH * 2);
    unsigned short* hA = (unsigned short*)alloc((size_t)N * DH * 2);
    unsigned short* hB = (unsigned short*)alloc((size_t)N * DH * 2);
    unsigned short* wt[8];
    for (int m = 0; m < 8; ++m) wt[m] = (unsigned short*)alloc(16384 * 2);
    int* cnt     = (int*)alloc((size_t)N * 4);
    int* rp_part = (int*)alloc((size_t)N * 4);
    int* row_ptr = (int*)alloc((size_t)(N + 1) * 4);
    int* rank    = (int*)alloc((size_t)E * 4);
    int* bsum    = (int*)alloc(256 * 4);
    int* esrc    = (int*)alloc((size_t)E * 4);

    WPrep wp;
    wp.src[0] = (const float*)d_in[2];
    wp.src[1] = (const float*)d_in[4];
    wp.src[2] = (const float*)d_in[6];
    wp.src[3] = (const float*)d_in[8];
    wp.src[4] = (const float*)d_in[10];
    wp.src[5] = (const float*)d_in[12];
    wp.src[6] = (const float*)d_in[14];
    wp.src[7] = (const float*)d_in[16];
    for (int m = 0; m < 8; ++m) wp.dst[m] = wt[m];
    int n4 = N * DH / 4;
    int prep_items = n4 + N + 7 * 16384 + 8192;
    prep_kernel<<<(prep_items + 255) / 256, 256, 0, stream>>>(x, xb, n4, wp, cnt, N);

    int nb = (N + 255) / 256;
    int eb = (E + 255) / 256;
    hist_kernel<<<eb, 256, 0, stream>>>(dstv, cnt, rank, E, N);
    scan1_kernel<<<nb, 256, 0, stream>>>(cnt, rp_part, bsum, N);
    scan2_kernel<<<1, 256, 0, stream>>>(bsum, nb);
    scan3_fill_kernel<<<eb, 256, 0, stream>>>(rp_part, bsum, row_ptr,
                                              src, dstv, rank, esrc, N, E);

    int gb = (N + 15) / 16;

    const float* c1b1 = (const float*)d_in[3];
    const float* c1b2 = (const float*)d_in[5];
    const float* c2b1 = (const float*)d_in[7];
    const float* c2b2 = (const float*)d_in[9];
    const float* c3b1 = (const float*)d_in[11];
    const float* c3b2 = (const float*)d_in[13];
    const float* l1b  = (const float*)d_in[15];
    const float* l2b  = (const float*)d_in[17];

    layer_kernel<false><<<gb, 256, 0, stream>>>(
        xb, row_ptr, esrc, wt[0], c1b1, wt[1], c1b2,
        nullptr, nullptr, nullptr, nullptr, hA, N);
    layer_kernel<false><<<gb, 256, 0, stream>>>(
        hA, row_ptr, esrc, wt[2], c2b1, wt[3], c2b2,
        nullptr, nullptr, nullptr, nullptr, hB, N);
    layer_kernel<true><<<gb, 256, 0, stream>>>(
        hB, row_ptr, esrc, wt[4], c3b1, wt[5], c3b2,
        wt[6], l1b, wt[7], l2b, d_out, N);
}

// Round 7
// 350.700 us; speedup vs baseline: 1.0386x; 1.0386x over previous
//
#include <hip/hip_runtime.h>
#include <hip/hip_bf16.h>

typedef __attribute__((ext_vector_type(8))) short bf16x8;
typedef __attribute__((ext_vector_type(4))) float f32x4;

#define DH 128
#define DOUT 64

static __device__ __forceinline__ unsigned short f2bf(float f) {
    __hip_bfloat16 h = __float2bfloat16(f);
    return *(unsigned short*)&h;
}
static __device__ __forceinline__ void acc2(float& a0, float& a1, unsigned int u) {
    a0 += __uint_as_float(u << 16);
    a1 += __uint_as_float(u & 0xffff0000u);
}
static __device__ __forceinline__ void accq(float* a, const uint4& u) {
    acc2(a[0], a[1], u.x);
    acc2(a[2], a[3], u.y);
    acc2(a[4], a[5], u.z);
    acc2(a[6], a[7], u.w);
}

// ---------------- prep: x->bf16, zero cnt, weights->bf16 transposed, zero rows, esrc=N ----------------

struct WPrep {
    const float* src[8];
    unsigned short* dst[8];
};

__global__ void prep_kernel(const float* __restrict__ x, unsigned short* __restrict__ xb,
                            unsigned short* __restrict__ hA, unsigned short* __restrict__ hB,
                            int n4, WPrep p, int* __restrict__ cnt,
                            int* __restrict__ esrc, int Epad, int N_) {
    int id = blockIdx.x * blockDim.x + threadIdx.x;
    if (id < n4) {
        float4 v = ((const float4*)x)[id];
        ushort4 b;
        b.x = f2bf(v.x); b.y = f2bf(v.y); b.z = f2bf(v.z); b.w = f2bf(v.w);
        ((ushort4*)xb)[id] = b;
        return;
    }
    id -= n4;
    if (id < N_) { cnt[id] = 0; return; }
    id -= N_;
    if (id < 7 * 16384 + 8192) {
        int m, off;
        if (id < 7 * 16384) { m = id >> 14; off = id & 16383; }
        else { m = 7; off = id - 7 * 16384; }
        int shift = (m == 7) ? 6 : 7;
        int nc = 1 << shift;
        int k = off >> shift;
        int n = off & (nc - 1);
        p.dst[m][n * 128 + k] = f2bf(p.src[m][off]);
        return;
    }
    id -= 7 * 16384 + 8192;
    if (id < 3 * 128) {
        int j = id & 127, w = id >> 7;
        if (w == 0) xb[(size_t)N_ * 128 + j] = 0;
        else if (w == 1) hA[(size_t)N_ * 128 + j] = 0;
        else hB[(size_t)N_ * 128 + j] = 0;
        return;
    }
    id -= 384;
    if (id < Epad) esrc[id] = N_;  // default: dummy edge -> zero row
}

// ---------------- CSR build (degrees padded to multiples of 16) ----------------

__global__ void hist_kernel(const int* __restrict__ dst, int* __restrict__ cnt,
                            int* __restrict__ rank, int E, int n) {
    int e = blockIdx.x * blockDim.x + threadIdx.x;
    if (e < E) {
        int d = dst[e];
        if ((unsigned)d < (unsigned)n) rank[e] = atomicAdd(&cnt[d], 1);
    }
}

// scan over padded degrees, domain [0, n] inclusive
__global__ void scan1_kernel(const int* __restrict__ cnt, int* __restrict__ rp_part,
                             int* __restrict__ bsum, int n) {
    __shared__ int s[256];
    int tid = threadIdx.x;
    int i = blockIdx.x * 256 + tid;
    int v = (i < n) ? ((cnt[i] + 15) & ~15) : 0;
    s[tid] = v;
    __syncthreads();
    for (int off = 1; off < 256; off <<= 1) {
        int t = (tid >= off) ? s[tid - off] : 0;
        __syncthreads();
        s[tid] += t;
        __syncthreads();
    }
    if (i <= n) rp_part[i] = s[tid] - v;
    if (tid == 255) bsum[blockIdx.x] = s[255];
}

__global__ void scan2_kernel(int* __restrict__ bsum, int nb) {
    __shared__ int s[256];
    int tid = threadIdx.x;
    int v = (tid < nb) ? bsum[tid] : 0;
    s[tid] = v;
    __syncthreads();
    for (int off = 1; off < 256; off <<= 1) {
        int t = (tid >= off) ? s[tid - off] : 0;
        __syncthreads();
        s[tid] += t;
        __syncthreads();
    }
    if (tid < nb) bsum[tid] = s[tid] - v;
}

// final padded row_ptr + atomic-free edge fill
__global__ void scan3_fill_kernel(const int* __restrict__ rp_part, const int* __restrict__ bsum,
                                  int* __restrict__ row_ptr,
                                  const int* __restrict__ src, const int* __restrict__ dst,
                                  const int* __restrict__ rank, int* __restrict__ esrc,
                                  int n, int E) {
    int gid = blockIdx.x * blockDim.x + threadIdx.x;
    if (gid <= n) row_ptr[gid] = rp_part[gid] + bsum[gid >> 8];
    if (gid < E) {
        int d = dst[gid];
        if ((unsigned)d < (unsigned)n)
            esrc[rp_part[d] + bsum[d >> 8] + rank[gid]] = src[gid];
    }
}

// ---------------- fused layer: agg -> GEMM1(relu) -> GEMM2 [-> GEMM3(relu) -> GEMM4] ----------------
// 16-row M tile, 256 threads (4 waves). Gather: branch-free fixed pipeline —
// per round 16 idx loads + 16 row loads (4 nodes x 4 edge-slots, lane = 16B chunk),
// dummies clamped to zero-row N via cndmask. Up to 16KB in flight per wave.

template <bool HEAD>
__launch_bounds__(256, 4)
__global__ void layer_kernel(const unsigned short* __restrict__ h,
                             const int* __restrict__ rp,
                             const int* __restrict__ esrc,
                             const unsigned short* __restrict__ W1t,
                             const float* __restrict__ b1,
                             const unsigned short* __restrict__ W2t,
                             const float* __restrict__ b2,
                             const unsigned short* __restrict__ W3t,
                             const float* __restrict__ b3,
                             const unsigned short* __restrict__ W4t,
                             const float* __restrict__ b4,
                             void* __restrict__ outp, int M) {
    constexpr int LDA = 128 + 8;
    __shared__ __align__(16) unsigned short As[16][LDA];
    __shared__ __align__(16) unsigned short Zs[16][LDA];

    int tid = threadIdx.x;
    int wave = __builtin_amdgcn_readfirstlane(tid >> 6);
    int lane = tid & 63;
    int grp = lane >> 4;   // edge-slot group 0..3
    int c = lane & 15;     // 16B chunk of a 256B row
    int row0 = blockIdx.x * 16;
    int nd0 = row0 + wave * 4;

    const uint4* hq = (const uint4*)h;  // row i chunk c at hq[i*16 + c]

    // self rows (issued early, independent)
    uint4 s[4];
#pragma unroll
    for (int i = 0; i < 4; ++i) s[i] = hq[(nd0 + i) * 16 + c];

    int b[4], rn[4];
#pragma unroll
    for (int i = 0; i < 4; ++i) {
        int rb = rp[nd0 + i], re = rp[nd0 + i + 1];
        b[i] = rb;
        rn[i] = (re - rb) >> 4;
    }

    float acc[4][8];
#pragma unroll
    for (int i = 0; i < 4; ++i)
#pragma unroll
        for (int j = 0; j < 8; ++j) acc[i][j] = 0.f;

    // add self once (group 0 only; cross-group reduce sums groups later)
    if (grp == 0) {
#pragma unroll
        for (int i = 0; i < 4; ++i) accq(acc[i], s[i]);
    }

    int maxr = max(max(rn[0], rn[1]), max(rn[2], rn[3]));
    for (int r = 0; r < maxr; ++r) {
#pragma unroll
        for (int half = 0; half < 2; ++half) {
            int idx[8];
#pragma unroll
            for (int t = 0; t < 8; ++t) {
                int i = half * 2 + (t >> 2);
                idx[t] = esrc[b[i] + (r << 4) + ((t & 3) << 2) + grp];
            }
#pragma unroll
            for (int t = 0; t < 8; ++t) {
                int i = half * 2 + (t >> 2);
                idx[t] = (r < rn[i]) ? idx[t] : M;  // rounds past this node's end -> zero row
            }
            uint4 u[8];
#pragma unroll
            for (int t = 0; t < 8; ++t) u[t] = hq[idx[t] * 16 + c];
#pragma unroll
            for (int t = 0; t < 8; ++t) accq(acc[half * 2 + (t >> 2)], u[t]);
        }
    }

    // cross-group reduce, pack to LDS
#pragma unroll
    for (int i = 0; i < 4; ++i) {
#pragma unroll
        for (int j = 0; j < 8; ++j) {
            float v = acc[i][j];
            v += __shfl_xor(v, 16, 64);
            v += __shfl_xor(v, 32, 64);
            acc[i][j] = v;
        }
        if (grp == 0) {
            uint4 ov;
            ov.x = (unsigned)f2bf(acc[i][0]) | ((unsigned)f2bf(acc[i][1]) << 16);
            ov.y = (unsigned)f2bf(acc[i][2]) | ((unsigned)f2bf(acc[i][3]) << 16);
            ov.z = (unsigned)f2bf(acc[i][4]) | ((unsigned)f2bf(acc[i][5]) << 16);
            ov.w = (unsigned)f2bf(acc[i][6]) | ((unsigned)f2bf(acc[i][7]) << 16);
            *(uint4*)(&As[wave * 4 + i][c * 8]) = ov;
        }
    }
    __syncthreads();

    int quad = lane >> 4;
    int l16 = lane & 15;

    // ---- GEMM1: Zs = relu(As @ W1 + b1) ----
    bf16x8 af[4];
#pragma unroll
    for (int kt = 0; kt < 4; ++kt)
        af[kt] = *(const bf16x8*)(&As[l16][kt * 32 + quad * 8]);
#pragma unroll
    for (int p = 0; p < 2; ++p) {
        int ncol = (wave * 2 + p) * 16 + l16;
        const unsigned short* wp = W1t + ncol * 128 + quad * 8;
        f32x4 a = {0.f, 0.f, 0.f, 0.f};
#pragma unroll
        for (int kt = 0; kt < 4; ++kt)
            a = __builtin_amdgcn_mfma_f32_16x16x32_bf16(
                af[kt], *(const bf16x8*)(wp + kt * 32), a, 0, 0, 0);
        float bs = b1[ncol];
#pragma unroll
        for (int r = 0; r < 4; ++r) {
            float v = a[r] + bs;
            if (v < 0.f) v = 0.f;
            Zs[quad * 4 + r][ncol] = f2bf(v);
        }
    }
    __syncthreads();

    // ---- GEMM2: relu(Zs @ W2 + b2) -> global bf16 (conv) or As (head) ----
    bf16x8 zf[4];
#pragma unroll
    for (int kt = 0; kt < 4; ++kt)
        zf[kt] = *(const bf16x8*)(&Zs[l16][kt * 32 + quad * 8]);
#pragma unroll
    for (int p = 0; p < 2; ++p) {
        int ncol = (wave * 2 + p) * 16 + l16;
        const unsigned short* wp = W2t + ncol * 128 + quad * 8;
        f32x4 a = {0.f, 0.f, 0.f, 0.f};
#pragma unroll
        for (int kt = 0; kt < 4; ++kt)
            a = __builtin_amdgcn_mfma_f32_16x16x32_bf16(
                zf[kt], *(const bf16x8*)(wp + kt * 32), a, 0, 0, 0);
        float bs = b2[ncol];
#pragma unroll
        for (int r = 0; r < 4; ++r) {
            float v = a[r] + bs;
            if (v < 0.f) v = 0.f;
            if (HEAD) {
                As[quad * 4 + r][ncol] = f2bf(v);
            } else {
                int grow = row0 + quad * 4 + r;
                if (grow < M)
                    ((unsigned short*)outp)[(size_t)grow * 128 + ncol] = f2bf(v);
            }
        }
    }

    if (HEAD) {
        __syncthreads();
        // ---- GEMM3: Zs = relu(As @ W3 + b3) ----
        bf16x8 hf[4];
#pragma unroll
        for (int kt = 0; kt < 4; ++kt)
            hf[kt] = *(const bf16x8*)(&As[l16][kt * 32 + quad * 8]);
#pragma unroll
        for (int p = 0; p < 2; ++p) {
            int ncol = (wave * 2 + p) * 16 + l16;
            const unsigned short* wp = W3t + ncol * 128 + quad * 8;
            f32x4 a = {0.f, 0.f, 0.f, 0.f};
#pragma unroll
            for (int kt = 0; kt < 4; ++kt)
                a = __builtin_amdgcn_mfma_f32_16x16x32_bf16(
                    hf[kt], *(const bf16x8*)(wp + kt * 32), a, 0, 0, 0);
            float bs = b3[ncol];
#pragma unroll
            for (int r = 0; r < 4; ++r) {
                float v = a[r] + bs;
                if (v < 0.f) v = 0.f;
                Zs[quad * 4 + r][ncol] = f2bf(v);
            }
        }
        __syncthreads();
        // ---- GEMM4: d_out = Zs @ W4 + b4 (fp32, 64 cols) ----
        bf16x8 gf[4];
#pragma unroll
        for (int kt = 0; kt < 4; ++kt)
            gf[kt] = *(const bf16x8*)(&Zs[l16][kt * 32 + quad * 8]);
        {
            int ncol = wave * 16 + l16;
            const unsigned short* wp = W4t + ncol * 128 + quad * 8;
            f32x4 a = {0.f, 0.f, 0.f, 0.f};
#pragma unroll
            for (int kt = 0; kt < 4; ++kt)
                a = __builtin_amdgcn_mfma_f32_16x16x32_bf16(
                    gf[kt], *(const bf16x8*)(wp + kt * 32), a, 0, 0, 0);
            float bs = b4[ncol];
#pragma unroll
            for (int r = 0; r < 4; ++r) {
                int grow = row0 + quad * 4 + r;
                if (grow < M)
                    ((float*)outp)[(size_t)grow * 64 + ncol] = a[r] + bs;
            }
        }
    }
}

// ---------------- launch ----------------

extern "C" void kernel_launch(void* const* d_in, const int* in_sizes, int n_in,
                              void* d_out, int out_size, void* d_ws, size_t ws_size,
                              hipStream_t stream) {
    const float* x = (const float*)d_in[0];
    const int* ei = (const int*)d_in[1];
    int N = in_sizes[0] / DH;
    int E = in_sizes[1] / 2;
    const int* src = ei;
    const int* dstv = ei + E;
    int Epad = E + 15 * N + 1024;  // worst-case padded edge count + slack

    char* ws = (char*)d_ws;
    size_t off = 0;
    auto alloc = [&](size_t bytes) -> void* {
        void* p = ws + off;
        off += (bytes + 255) & ~(size_t)255;
        return p;
    };
    // feature buffers have N+1 rows; row N is the zero row
    unsigned short* xb = (unsigned short*)alloc((size_t)(N + 1) * DH * 2);
    unsigned short* hA = (unsigned short*)alloc((size_t)(N + 1) * DH * 2);
    unsigned short* hB = (unsigned short*)alloc((size_t)(N + 1) * DH * 2);
    unsigned short* wt[8];
    for (int m = 0; m < 8; ++m) wt[m] = (unsigned short*)alloc(16384 * 2);
    int* cnt     = (int*)alloc((size_t)N * 4);
    int* rp_part = (int*)alloc((size_t)(N + 1) * 4);
    int* row_ptr = (int*)alloc((size_t)(N + 1) * 4);
    int* rank    = (int*)alloc((size_t)E * 4);
    int* bsum    = (int*)alloc(256 * 4);
    int* esrc    = (int*)alloc((size_t)Epad * 4);

    WPrep wp;
    wp.src[0] = (const float*)d_in[2];
    wp.src[1] = (const float*)d_in[4];
    wp.src[2] = (const float*)d_in[6];
    wp.src[3] = (const float*)d_in[8];
    wp.src[4] = (const float*)d_in[10];
    wp.src[5] = (const float*)d_in[12];
    wp.src[6] = (const float*)d_in[14];
    wp.src[7] = (const float*)d_in[16];
    for (int m = 0; m < 8; ++m) wp.dst[m] = wt[m];
    int n4 = N * DH / 4;
    int prep_items = n4 + N + 7 * 16384 + 8192 + 384 + Epad;
    prep_kernel<<<(prep_items + 255) / 256, 256, 0, stream>>>(
        x, xb, hA, hB, n4, wp, cnt, esrc, Epad, N);

    int nb = (N + 1 + 255) / 256;
    int eb = (E + 255) / 256;
    hist_kernel<<<eb, 256, 0, stream>>>(dstv, cnt, rank, E, N);
    scan1_kernel<<<nb, 256, 0, stream>>>(cnt, rp_part, bsum, N);
    scan2_kernel<<<1, 256, 0, stream>>>(bsum, nb);
    scan3_fill_kernel<<<eb, 256, 0, stream>>>(rp_part, bsum, row_ptr,
                                              src, dstv, rank, esrc, N, E);

    int gb = (N + 15) / 16;

    const float* c1b1 = (const float*)d_in[3];
    const float* c1b2 = (const float*)d_in[5];
    const float* c2b1 = (const float*)d_in[7];
    const float* c2b2 = (const float*)d_in[9];
    const float* c3b1 = (const float*)d_in[11];
    const float* c3b2 = (const float*)d_in[13];
    const float* l1b  = (const float*)d_in[15];
    const float* l2b  = (const float*)d_in[17];

    layer_kernel<false><<<gb, 256, 0, stream>>>(
        xb, row_ptr, esrc, wt[0], c1b1, wt[1], c1b2,
        nullptr, nullptr, nullptr, nullptr, hA, N);
    layer_kernel<false><<<gb, 256, 0, stream>>>(
        hA, row_ptr, esrc, wt[2], c2b1, wt[3], c2b2,
        nullptr, nullptr, nullptr, nullptr, hB, N);
    layer_kernel<true><<<gb, 256, 0, stream>>>(
        hB, row_ptr, esrc, wt[4], c3b1, wt[5], c3b2,
        wt[6], l1b, wt[7], l2b, d_out, N);
}

// Round 8
// 323.665 us; speedup vs baseline: 1.1254x; 1.0835x over previous
//
#include <hip/hip_runtime.h>
#include <hip/hip_bf16.h>

typedef __attribute__((ext_vector_type(8))) short bf16x8;
typedef __attribute__((ext_vector_type(4))) float f32x4;

#define DH 128
#define DOUT 64

static __device__ __forceinline__ unsigned short f2bf(float f) {
    __hip_bfloat16 h = __float2bfloat16(f);
    return *(unsigned short*)&h;
}
static __device__ __forceinline__ void acc2(float& a0, float& a1, unsigned int u) {
    a0 += __uint_as_float(u << 16);
    a1 += __uint_as_float(u & 0xffff0000u);
}

// ---------------- prep: x->bf16, zero cnt, weights->bf16 transposed, zero rows, esrc default ----------------

struct WPrep {
    const float* src[8];
    unsigned short* dst[8];
};

__global__ void prep_kernel(const float* __restrict__ x, unsigned short* __restrict__ xb,
                            unsigned short* __restrict__ hA, unsigned short* __restrict__ hB,
                            int n4, WPrep p, int* __restrict__ cnt,
                            int* __restrict__ esrc, int Epad, int N_) {
    int id = blockIdx.x * blockDim.x + threadIdx.x;
    if (id < n4) {
        float4 v = ((const float4*)x)[id];
        ushort4 b;
        b.x = f2bf(v.x); b.y = f2bf(v.y); b.z = f2bf(v.z); b.w = f2bf(v.w);
        ((ushort4*)xb)[id] = b;
        return;
    }
    id -= n4;
    if (id < N_) { cnt[id] = 0; return; }
    id -= N_;
    if (id < 7 * 16384 + 8192) {
        int m, off;
        if (id < 7 * 16384) { m = id >> 14; off = id & 16383; }
        else { m = 7; off = id - 7 * 16384; }
        int shift = (m == 7) ? 6 : 7;
        int nc = 1 << shift;
        int k = off >> shift;
        int n = off & (nc - 1);
        p.dst[m][n * 128 + k] = f2bf(p.src[m][off]);
        return;
    }
    id -= 7 * 16384 + 8192;
    if (id < 3 * 128) {
        int j = id & 127, w = id >> 7;
        if (w == 0) xb[(size_t)N_ * 128 + j] = 0;
        else if (w == 1) hA[(size_t)N_ * 128 + j] = 0;
        else hB[(size_t)N_ * 128 + j] = 0;
        return;
    }
    id -= 384;
    if (id < Epad) esrc[id] = N_ << 8;  // dummy edge -> byte offset of zero row
}

// ---------------- CSR build (degrees padded to multiples of 8; esrc holds byte offsets) ----------------

__global__ void hist_kernel(const int* __restrict__ dst, int* __restrict__ cnt,
                            int* __restrict__ rank, int E, int n) {
    int e = blockIdx.x * blockDim.x + threadIdx.x;
    if (e < E) {
        int d = dst[e];
        if ((unsigned)d < (unsigned)n) rank[e] = atomicAdd(&cnt[d], 1);
    }
}

__global__ void scan1_kernel(const int* __restrict__ cnt, int* __restrict__ rp_part,
                             int* __restrict__ bsum, int n) {
    __shared__ int s[256];
    int tid = threadIdx.x;
    int i = blockIdx.x * 256 + tid;
    int v = (i < n) ? ((cnt[i] + 7) & ~7) : 0;
    s[tid] = v;
    __syncthreads();
    for (int off = 1; off < 256; off <<= 1) {
        int t = (tid >= off) ? s[tid - off] : 0;
        __syncthreads();
        s[tid] += t;
        __syncthreads();
    }
    if (i <= n) rp_part[i] = s[tid] - v;
    if (tid == 255) bsum[blockIdx.x] = s[255];
}

__global__ void scan2_kernel(int* __restrict__ bsum, int nb) {
    __shared__ int s[256];
    int tid = threadIdx.x;
    int v = (tid < nb) ? bsum[tid] : 0;
    s[tid] = v;
    __syncthreads();
    for (int off = 1; off < 256; off <<= 1) {
        int t = (tid >= off) ? s[tid - off] : 0;
        __syncthreads();
        s[tid] += t;
        __syncthreads();
    }
    if (tid < nb) bsum[tid] = s[tid] - v;
}

__global__ void scan3_fill_kernel(const int* __restrict__ rp_part, const int* __restrict__ bsum,
                                  int* __restrict__ row_ptr,
                                  const int* __restrict__ src, const int* __restrict__ dst,
                                  const int* __restrict__ rank, int* __restrict__ esrc,
                                  int n, int E) {
    int gid = blockIdx.x * blockDim.x + threadIdx.x;
    if (gid <= n) row_ptr[gid] = rp_part[gid] + bsum[gid >> 8];
    if (gid < E) {
        int d = dst[gid];
        if ((unsigned)d < (unsigned)n)
            esrc[rp_part[d] + bsum[d >> 8] + rank[gid]] = src[gid] << 8;  // byte offset
    }
}

// ---------------- fused layer: agg -> GEMM1(relu) -> GEMM2 [-> GEMM3(relu) -> GEMM4] ----------------
// 16-row M tile, 256 threads (4 waves). Gather: per node, branch-free batches of 8
// whole-wave row loads (SGPR base per edge via readfirstlane'd prescaled offsets,
// voffset = lane*4) -> ~4 VALU/edge, 8 rows in flight. Zero-row dummies absorb padding.

template <bool HEAD>
__launch_bounds__(256, 8)
__global__ void layer_kernel(const unsigned short* __restrict__ h,
                             const int* __restrict__ rp,
                             const int* __restrict__ esrc,
                             const unsigned short* __restrict__ W1t,
                             const float* __restrict__ b1,
                             const unsigned short* __restrict__ W2t,
                             const float* __restrict__ b2,
                             const unsigned short* __restrict__ W3t,
                             const float* __restrict__ b3,
                             const unsigned short* __restrict__ W4t,
                             const float* __restrict__ b4,
                             void* __restrict__ outp, int M) {
    constexpr int LDA = 128 + 8;
    __shared__ __align__(16) unsigned short As[16][LDA];
    __shared__ __align__(16) unsigned short Zs[16][LDA];

    int tid = threadIdx.x;
    int wave = __builtin_amdgcn_readfirstlane(tid >> 6);
    int lane = tid & 63;
    int row0 = blockIdx.x * 16;
    int nd0 = row0 + wave * 4;

    const char* hc = (const char*)h;
    unsigned voff = (unsigned)lane << 2;

    // ---- gather: 4 nodes sequential, degree-adaptive 8-deep batches ----
#pragma unroll
    for (int i = 0; i < 4; ++i) {
        int nd = nd0 + i;
        int rb = __builtin_amdgcn_readfirstlane(rp[nd]);
        int re = __builtin_amdgcn_readfirstlane(rp[nd + 1]);
        unsigned su = *(const unsigned*)(hc + ((size_t)(unsigned)nd << 8) + voff);
        float a0 = 0.f, a1 = 0.f;
        for (int r = rb; r < re; r += 8) {
            int o0 = __builtin_amdgcn_readfirstlane(esrc[r + 0]);
            int o1 = __builtin_amdgcn_readfirstlane(esrc[r + 1]);
            int o2 = __builtin_amdgcn_readfirstlane(esrc[r + 2]);
            int o3 = __builtin_amdgcn_readfirstlane(esrc[r + 3]);
            int o4 = __builtin_amdgcn_readfirstlane(esrc[r + 4]);
            int o5 = __builtin_amdgcn_readfirstlane(esrc[r + 5]);
            int o6 = __builtin_amdgcn_readfirstlane(esrc[r + 6]);
            int o7 = __builtin_amdgcn_readfirstlane(esrc[r + 7]);
            unsigned u0 = *(const unsigned*)(hc + o0 + voff);
            unsigned u1 = *(const unsigned*)(hc + o1 + voff);
            unsigned u2 = *(const unsigned*)(hc + o2 + voff);
            unsigned u3 = *(const unsigned*)(hc + o3 + voff);
            unsigned u4 = *(const unsigned*)(hc + o4 + voff);
            unsigned u5 = *(const unsigned*)(hc + o5 + voff);
            unsigned u6 = *(const unsigned*)(hc + o6 + voff);
            unsigned u7 = *(const unsigned*)(hc + o7 + voff);
            acc2(a0, a1, u0);
            acc2(a0, a1, u1);
            acc2(a0, a1, u2);
            acc2(a0, a1, u3);
            acc2(a0, a1, u4);
            acc2(a0, a1, u5);
            acc2(a0, a1, u6);
            acc2(a0, a1, u7);
        }
        acc2(a0, a1, su);  // self (loaded early, consumed last)
        unsigned pv = (unsigned)f2bf(a0) | ((unsigned)f2bf(a1) << 16);
        *(unsigned*)&As[wave * 4 + i][lane * 2] = pv;
    }
    __syncthreads();

    int quad = lane >> 4;
    int l16 = lane & 15;

    // ---- GEMM1: Zs = relu(As @ W1 + b1) ----
    bf16x8 af[4];
#pragma unroll
    for (int kt = 0; kt < 4; ++kt)
        af[kt] = *(const bf16x8*)(&As[l16][kt * 32 + quad * 8]);
#pragma unroll
    for (int p = 0; p < 2; ++p) {
        int ncol = (wave * 2 + p) * 16 + l16;
        const unsigned short* wp = W1t + ncol * 128 + quad * 8;
        f32x4 a = {0.f, 0.f, 0.f, 0.f};
#pragma unroll
        for (int kt = 0; kt < 4; ++kt)
            a = __builtin_amdgcn_mfma_f32_16x16x32_bf16(
                af[kt], *(const bf16x8*)(wp + kt * 32), a, 0, 0, 0);
        float bs = b1[ncol];
#pragma unroll
        for (int r = 0; r < 4; ++r) {
            float v = a[r] + bs;
            if (v < 0.f) v = 0.f;
            Zs[quad * 4 + r][ncol] = f2bf(v);
        }
    }
    __syncthreads();

    // ---- GEMM2: relu(Zs @ W2 + b2) -> global bf16 (conv) or As (head) ----
    bf16x8 zf[4];
#pragma unroll
    for (int kt = 0; kt < 4; ++kt)
        zf[kt] = *(const bf16x8*)(&Zs[l16][kt * 32 + quad * 8]);
#pragma unroll
    for (int p = 0; p < 2; ++p) {
        int ncol = (wave * 2 + p) * 16 + l16;
        const unsigned short* wp = W2t + ncol * 128 + quad * 8;
        f32x4 a = {0.f, 0.f, 0.f, 0.f};
#pragma unroll
        for (int kt = 0; kt < 4; ++kt)
            a = __builtin_amdgcn_mfma_f32_16x16x32_bf16(
                zf[kt], *(const bf16x8*)(wp + kt * 32), a, 0, 0, 0);
        float bs = b2[ncol];
#pragma unroll
        for (int r = 0; r < 4; ++r) {
            float v = a[r] + bs;
            if (v < 0.f) v = 0.f;
            if (HEAD) {
                As[quad * 4 + r][ncol] = f2bf(v);
            } else {
                int grow = row0 + quad * 4 + r;
                if (grow < M)
                    ((unsigned short*)outp)[(size_t)grow * 128 + ncol] = f2bf(v);
            }
        }
    }

    if (HEAD) {
        __syncthreads();
        // ---- GEMM3: Zs = relu(As @ W3 + b3) ----
        bf16x8 hf[4];
#pragma unroll
        for (int kt = 0; kt < 4; ++kt)
            hf[kt] = *(const bf16x8*)(&As[l16][kt * 32 + quad * 8]);
#pragma unroll
        for (int p = 0; p < 2; ++p) {
            int ncol = (wave * 2 + p) * 16 + l16;
            const unsigned short* wp = W3t + ncol * 128 + quad * 8;
            f32x4 a = {0.f, 0.f, 0.f, 0.f};
#pragma unroll
            for (int kt = 0; kt < 4; ++kt)
                a = __builtin_amdgcn_mfma_f32_16x16x32_bf16(
                    hf[kt], *(const bf16x8*)(wp + kt * 32), a, 0, 0, 0);
            float bs = b3[ncol];
#pragma unroll
            for (int r = 0; r < 4; ++r) {
                float v = a[r] + bs;
                if (v < 0.f) v = 0.f;
                Zs[quad * 4 + r][ncol] = f2bf(v);
            }
        }
        __syncthreads();
        // ---- GEMM4: d_out = Zs @ W4 + b4 (fp32, 64 cols) ----
        bf16x8 gf[4];
#pragma unroll
        for (int kt = 0; kt < 4; ++kt)
            gf[kt] = *(const bf16x8*)(&Zs[l16][kt * 32 + quad * 8]);
        {
            int ncol = wave * 16 + l16;
            const unsigned short* wp = W4t + ncol * 128 + quad * 8;
            f32x4 a = {0.f, 0.f, 0.f, 0.f};
#pragma unroll
            for (int kt = 0; kt < 4; ++kt)
                a = __builtin_amdgcn_mfma_f32_16x16x32_bf16(
                    gf[kt], *(const bf16x8*)(wp + kt * 32), a, 0, 0, 0);
            float bs = b4[ncol];
#pragma unroll
            for (int r = 0; r < 4; ++r) {
                int grow = row0 + quad * 4 + r;
                if (grow < M)
                    ((float*)outp)[(size_t)grow * 64 + ncol] = a[r] + bs;
            }
        }
    }
}

// ---------------- launch ----------------

extern "C" void kernel_launch(void* const* d_in, const int* in_sizes, int n_in,
                              void* d_out, int out_size, void* d_ws, size_t ws_size,
                              hipStream_t stream) {
    const float* x = (const float*)d_in[0];
    const int* ei = (const int*)d_in[1];
    int N = in_sizes[0] / DH;
    int E = in_sizes[1] / 2;
    const int* src = ei;
    const int* dstv = ei + E;
    int Epad = E + 7 * N + 1024;  // worst-case padded edge count + slack

    char* ws = (char*)d_ws;
    size_t off = 0;
    auto alloc = [&](size_t bytes) -> void* {
        void* p = ws + off;
        off += (bytes + 255) & ~(size_t)255;
        return p;
    };
    // feature buffers have N+1 rows; row N is the zero row
    unsigned short* xb = (unsigned short*)alloc((size_t)(N + 1) * DH * 2);
    unsigned short* hA = (unsigned short*)alloc((size_t)(N + 1) * DH * 2);
    unsigned short* hB = (unsigned short*)alloc((size_t)(N + 1) * DH * 2);
    unsigned short* wt[8];
    for (int m = 0; m < 8; ++m) wt[m] = (unsigned short*)alloc(16384 * 2);
    int* cnt     = (int*)alloc((size_t)N * 4);
    int* rp_part = (int*)alloc((size_t)(N + 1) * 4);
    int* row_ptr = (int*)alloc((size_t)(N + 1) * 4);
    int* rank    = (int*)alloc((size_t)E * 4);
    int* bsum    = (int*)alloc(256 * 4);
    int* esrc    = (int*)alloc((size_t)Epad * 4);

    WPrep wp;
    wp.src[0] = (const float*)d_in[2];
    wp.src[1] = (const float*)d_in[4];
    wp.src[2] = (const float*)d_in[6];
    wp.src[3] = (const float*)d_in[8];
    wp.src[4] = (const float*)d_in[10];
    wp.src[5] = (const float*)d_in[12];
    wp.src[6] = (const float*)d_in[14];
    wp.src[7] = (const float*)d_in[16];
    for (int m = 0; m < 8; ++m) wp.dst[m] = wt[m];
    int n4 = N * DH / 4;
    int prep_items = n4 + N + 7 * 16384 + 8192 + 384 + Epad;
    prep_kernel<<<(prep_items + 255) / 256, 256, 0, stream>>>(
        x, xb, hA, hB, n4, wp, cnt, esrc, Epad, N);

    int nb = (N + 1 + 255) / 256;
    int eb = (E + 255) / 256;
    hist_kernel<<<eb, 256, 0, stream>>>(dstv, cnt, rank, E, N);
    scan1_kernel<<<nb, 256, 0, stream>>>(cnt, rp_part, bsum, N);
    scan2_kernel<<<1, 256, 0, stream>>>(bsum, nb);
    scan3_fill_kernel<<<eb, 256, 0, stream>>>(rp_part, bsum, row_ptr,
                                              src, dstv, rank, esrc, N, E);

    int gb = (N + 15) / 16;

    const float* c1b1 = (const float*)d_in[3];
    const float* c1b2 = (const float*)d_in[5];
    const float* c2b1 = (const float*)d_in[7];
    const float* c2b2 = (const float*)d_in[9];
    const float* c3b1 = (const float*)d_in[11];
    const float* c3b2 = (const float*)d_in[13];
    const float* l1b  = (const float*)d_in[15];
    const float* l2b  = (const float*)d_in[17];

    layer_kernel<false><<<gb, 256, 0, stream>>>(
        xb, row_ptr, esrc, wt[0], c1b1, wt[1], c1b2,
        nullptr, nullptr, nullptr, nullptr, hA, N);
    layer_kernel<false><<<gb, 256, 0, stream>>>(
        hA, row_ptr, esrc, wt[2], c2b1, wt[3], c2b2,
        nullptr, nullptr, nullptr, nullptr, hB, N);
    layer_kernel<true><<<gb, 256, 0, stream>>>(
        hB, row_ptr, esrc, wt[4], c3b1, wt[5], c3b2,
        wt[6], l1b, wt[7], l2b, d_out, N);
}

// Round 9
// 321.549 us; speedup vs baseline: 1.1328x; 1.0066x over previous
//
#include <hip/hip_runtime.h>
#include <hip/hip_bf16.h>

typedef __attribute__((ext_vector_type(8))) short bf16x8;
typedef __attribute__((ext_vector_type(4))) float f32x4;

#define DH 128
#define DOUT 64

static __device__ __forceinline__ unsigned short f2bf(float f) {
    __hip_bfloat16 h = __float2bfloat16(f);
    return *(unsigned short*)&h;
}
static __device__ __forceinline__ void acc2(float& a0, float& a1, unsigned int u) {
    a0 += __uint_as_float(u << 16);
    a1 += __uint_as_float(u & 0xffff0000u);
}

// ---------------- prep: x->bf16, zero cnt, weights->bf16 transposed, zero rows, esrc default ----------------

struct WPrep {
    const float* src[8];
    unsigned short* dst[8];
};

__global__ void prep_kernel(const float* __restrict__ x, unsigned short* __restrict__ xb,
                            unsigned short* __restrict__ hA, unsigned short* __restrict__ hB,
                            int n4, WPrep p, int* __restrict__ cnt,
                            int* __restrict__ esrc, int Epad, int N_) {
    int id = blockIdx.x * blockDim.x + threadIdx.x;
    if (id < n4) {
        float4 v = ((const float4*)x)[id];
        ushort4 b;
        b.x = f2bf(v.x); b.y = f2bf(v.y); b.z = f2bf(v.z); b.w = f2bf(v.w);
        ((ushort4*)xb)[id] = b;
        return;
    }
    id -= n4;
    if (id < N_) { cnt[id] = 0; return; }
    id -= N_;
    if (id < 7 * 16384 + 8192) {
        int m, off;
        if (id < 7 * 16384) { m = id >> 14; off = id & 16383; }
        else { m = 7; off = id - 7 * 16384; }
        int shift = (m == 7) ? 6 : 7;
        int nc = 1 << shift;
        int k = off >> shift;
        int n = off & (nc - 1);
        p.dst[m][n * 128 + k] = f2bf(p.src[m][off]);
        return;
    }
    id -= 7 * 16384 + 8192;
    if (id < 3 * 128) {
        int j = id & 127, w = id >> 7;
        if (w == 0) xb[(size_t)N_ * 128 + j] = 0;
        else if (w == 1) hA[(size_t)N_ * 128 + j] = 0;
        else hB[(size_t)N_ * 128 + j] = 0;
        return;
    }
    id -= 384;
    if (id < Epad) esrc[id] = N_ << 8;  // dummy edge -> byte offset of zero row
}

// ---------------- CSR build (degrees padded to multiples of 8; esrc holds byte offsets) ----------------

__global__ void hist_kernel(const int* __restrict__ dst, int* __restrict__ cnt,
                            int* __restrict__ rank, int E, int n) {
    int e = blockIdx.x * blockDim.x + threadIdx.x;
    if (e < E) {
        int d = dst[e];
        if ((unsigned)d < (unsigned)n) rank[e] = atomicAdd(&cnt[d], 1);
    }
}

__global__ void scan1_kernel(const int* __restrict__ cnt, int* __restrict__ rp_part,
                             int* __restrict__ bsum, int n) {
    __shared__ int s[256];
    int tid = threadIdx.x;
    int i = blockIdx.x * 256 + tid;
    int v = (i < n) ? ((cnt[i] + 7) & ~7) : 0;
    s[tid] = v;
    __syncthreads();
    for (int off = 1; off < 256; off <<= 1) {
        int t = (tid >= off) ? s[tid - off] : 0;
        __syncthreads();
        s[tid] += t;
        __syncthreads();
    }
    if (i <= n) rp_part[i] = s[tid] - v;
    if (tid == 255) bsum[blockIdx.x] = s[255];
}

__global__ void scan2_kernel(int* __restrict__ bsum, int nb) {
    __shared__ int s[256];
    int tid = threadIdx.x;
    int v = (tid < nb) ? bsum[tid] : 0;
    s[tid] = v;
    __syncthreads();
    for (int off = 1; off < 256; off <<= 1) {
        int t = (tid >= off) ? s[tid - off] : 0;
        __syncthreads();
        s[tid] += t;
        __syncthreads();
    }
    if (tid < nb) bsum[tid] = s[tid] - v;
}

__global__ void scan3_fill_kernel(const int* __restrict__ rp_part, const int* __restrict__ bsum,
                                  int* __restrict__ row_ptr,
                                  const int* __restrict__ src, const int* __restrict__ dst,
                                  const int* __restrict__ rank, int* __restrict__ esrc,
                                  int n, int E) {
    int gid = blockIdx.x * blockDim.x + threadIdx.x;
    if (gid <= n) row_ptr[gid] = rp_part[gid] + bsum[gid >> 8];
    if (gid < E) {
        int d = dst[gid];
        if ((unsigned)d < (unsigned)n)
            esrc[rp_part[d] + bsum[d >> 8] + rank[gid]] = src[gid] << 8;  // byte offset
    }
}

// ---------------- fused layer: agg -> GEMM1(relu) -> GEMM2 [-> GEMM3(relu) -> GEMM4] ----------------
// 16-row M tile, 256 threads (4 waves). Gather: block's contiguous CSR edge window
// staged into LDS (coalesced); index reads become ds_read broadcasts (lgkmcnt) fully
// decoupled from the row-load vmcnt FIFO. Per node: 2x8 software-pipelined whole-wave
// 256B row loads (~16 rows / 4KB in flight). Zero-row dummies absorb x8 padding.

template <bool HEAD>
__launch_bounds__(256, 6)
__global__ void layer_kernel(const unsigned short* __restrict__ h,
                             const int* __restrict__ rp,
                             const int* __restrict__ esrc,
                             const unsigned short* __restrict__ W1t,
                             const float* __restrict__ b1,
                             const unsigned short* __restrict__ W2t,
                             const float* __restrict__ b2,
                             const unsigned short* __restrict__ W3t,
                             const float* __restrict__ b3,
                             const unsigned short* __restrict__ W4t,
                             const float* __restrict__ b4,
                             void* __restrict__ outp, int M) {
    constexpr int LDA = 128 + 8;
    constexpr int CAP = 2048;
    __shared__ __align__(16) unsigned short As[16][LDA];
    __shared__ __align__(16) unsigned short Zs[16][LDA];
    __shared__ int sIdx[CAP];

    int tid = threadIdx.x;
    int wave = __builtin_amdgcn_readfirstlane(tid >> 6);
    int lane = tid & 63;
    int row0 = blockIdx.x * 16;
    int nd0 = row0 + wave * 4;

    const char* hc = (const char*)h;
    unsigned voff = (unsigned)lane << 2;

    int wb = rp[row0];
    int C = rp[min(row0 + 16, M)] - wb;

    // per-node windows (relative to wb) + self rows; accumulators persist across passes
    int b[4], e[4];
    unsigned su[4];
    float a0[4] = {0.f, 0.f, 0.f, 0.f}, a1[4] = {0.f, 0.f, 0.f, 0.f};
#pragma unroll
    for (int i = 0; i < 4; ++i) {
        int nd = nd0 + i;
        int ndc = min(nd, M);
        int nd1 = min(nd + 1, M);
        b[i] = rp[ndc] - wb;
        e[i] = rp[nd1] - wb;
        su[i] = *(const unsigned*)(hc + ((size_t)(unsigned)ndc << 8) + voff);
    }

    for (int p0 = 0; p0 < C; p0 += CAP) {
        int cend = min(C, p0 + CAP);
        for (int i = tid; i < cend - p0; i += 256) sIdx[i] = esrc[wb + p0 + i];
        __syncthreads();
#pragma unroll
        for (int i = 0; i < 4; ++i) {
            int nb = max(b[i], p0) - p0;
            int ne = min(e[i], cend) - p0;
            if (nb < ne) {
                int idxA[8];
                unsigned uA[8];
#pragma unroll
                for (int t = 0; t < 8; ++t) idxA[t] = sIdx[nb + t];
#pragma unroll
                for (int t = 0; t < 8; ++t)
                    uA[t] = *(const unsigned*)(hc + (unsigned)idxA[t] + voff);
                for (int r = nb + 8; r < ne; r += 8) {
                    int idxB[8];
                    unsigned uB[8];
#pragma unroll
                    for (int t = 0; t < 8; ++t) idxB[t] = sIdx[r + t];
#pragma unroll
                    for (int t = 0; t < 8; ++t)
                        uB[t] = *(const unsigned*)(hc + (unsigned)idxB[t] + voff);
#pragma unroll
                    for (int t = 0; t < 8; ++t) acc2(a0[i], a1[i], uA[t]);
#pragma unroll
                    for (int t = 0; t < 8; ++t) { uA[t] = uB[t]; }
                }
#pragma unroll
                for (int t = 0; t < 8; ++t) acc2(a0[i], a1[i], uA[t]);
            }
        }
        __syncthreads();
    }

    // add self, pack to LDS
#pragma unroll
    for (int i = 0; i < 4; ++i) {
        acc2(a0[i], a1[i], su[i]);
        unsigned pv = (unsigned)f2bf(a0[i]) | ((unsigned)f2bf(a1[i]) << 16);
        *(unsigned*)&As[wave * 4 + i][lane * 2] = pv;
    }
    __syncthreads();

    int quad = lane >> 4;
    int l16 = lane & 15;

    // ---- GEMM1: Zs = relu(As @ W1 + b1) ----
    bf16x8 af[4];
#pragma unroll
    for (int kt = 0; kt < 4; ++kt)
        af[kt] = *(const bf16x8*)(&As[l16][kt * 32 + quad * 8]);
#pragma unroll
    for (int p = 0; p < 2; ++p) {
        int ncol = (wave * 2 + p) * 16 + l16;
        const unsigned short* wp = W1t + ncol * 128 + quad * 8;
        f32x4 a = {0.f, 0.f, 0.f, 0.f};
#pragma unroll
        for (int kt = 0; kt < 4; ++kt)
            a = __builtin_amdgcn_mfma_f32_16x16x32_bf16(
                af[kt], *(const bf16x8*)(wp + kt * 32), a, 0, 0, 0);
        float bs = b1[ncol];
#pragma unroll
        for (int r = 0; r < 4; ++r) {
            float v = a[r] + bs;
            if (v < 0.f) v = 0.f;
            Zs[quad * 4 + r][ncol] = f2bf(v);
        }
    }
    __syncthreads();

    // ---- GEMM2: relu(Zs @ W2 + b2) -> global bf16 (conv) or As (head) ----
    bf16x8 zf[4];
#pragma unroll
    for (int kt = 0; kt < 4; ++kt)
        zf[kt] = *(const bf16x8*)(&Zs[l16][kt * 32 + quad * 8]);
#pragma unroll
    for (int p = 0; p < 2; ++p) {
        int ncol = (wave * 2 + p) * 16 + l16;
        const unsigned short* wp = W2t + ncol * 128 + quad * 8;
        f32x4 a = {0.f, 0.f, 0.f, 0.f};
#pragma unroll
        for (int kt = 0; kt < 4; ++kt)
            a = __builtin_amdgcn_mfma_f32_16x16x32_bf16(
                zf[kt], *(const bf16x8*)(wp + kt * 32), a, 0, 0, 0);
        float bs = b2[ncol];
#pragma unroll
        for (int r = 0; r < 4; ++r) {
            float v = a[r] + bs;
            if (v < 0.f) v = 0.f;
            if (HEAD) {
                As[quad * 4 + r][ncol] = f2bf(v);
            } else {
                int grow = row0 + quad * 4 + r;
                if (grow < M)
                    ((unsigned short*)outp)[(size_t)grow * 128 + ncol] = f2bf(v);
            }
        }
    }

    if (HEAD) {
        __syncthreads();
        // ---- GEMM3: Zs = relu(As @ W3 + b3) ----
        bf16x8 hf[4];
#pragma unroll
        for (int kt = 0; kt < 4; ++kt)
            hf[kt] = *(const bf16x8*)(&As[l16][kt * 32 + quad * 8]);
#pragma unroll
        for (int p = 0; p < 2; ++p) {
            int ncol = (wave * 2 + p) * 16 + l16;
            const unsigned short* wp = W3t + ncol * 128 + quad * 8;
            f32x4 a = {0.f, 0.f, 0.f, 0.f};
#pragma unroll
            for (int kt = 0; kt < 4; ++kt)
                a = __builtin_amdgcn_mfma_f32_16x16x32_bf16(
                    hf[kt], *(const bf16x8*)(wp + kt * 32), a, 0, 0, 0);
            float bs = b3[ncol];
#pragma unroll
            for (int r = 0; r < 4; ++r) {
                float v = a[r] + bs;
                if (v < 0.f) v = 0.f;
                Zs[quad * 4 + r][ncol] = f2bf(v);
            }
        }
        __syncthreads();
        // ---- GEMM4: d_out = Zs @ W4 + b4 (fp32, 64 cols) ----
        bf16x8 gf[4];
#pragma unroll
        for (int kt = 0; kt < 4; ++kt)
            gf[kt] = *(const bf16x8*)(&Zs[l16][kt * 32 + quad * 8]);
        {
            int ncol = wave * 16 + l16;
            const unsigned short* wp = W4t + ncol * 128 + quad * 8;
            f32x4 a = {0.f, 0.f, 0.f, 0.f};
#pragma unroll
            for (int kt = 0; kt < 4; ++kt)
                a = __builtin_amdgcn_mfma_f32_16x16x32_bf16(
                    gf[kt], *(const bf16x8*)(wp + kt * 32), a, 0, 0, 0);
            float bs = b4[ncol];
#pragma unroll
            for (int r = 0; r < 4; ++r) {
                int grow = row0 + quad * 4 + r;
                if (grow < M)
                    ((float*)outp)[(size_t)grow * 64 + ncol] = a[r] + bs;
            }
        }
    }
}

// ---------------- launch ----------------

extern "C" void kernel_launch(void* const* d_in, const int* in_sizes, int n_in,
                              void* d_out, int out_size, void* d_ws, size_t ws_size,
                              hipStream_t stream) {
    const float* x = (const float*)d_in[0];
    const int* ei = (const int*)d_in[1];
    int N = in_sizes[0] / DH;
    int E = in_sizes[1] / 2;
    const int* src = ei;
    const int* dstv = ei + E;
    int Epad = E + 7 * N + 1024;  // worst-case padded edge count + slack

    char* ws = (char*)d_ws;
    size_t off = 0;
    auto alloc = [&](size_t bytes) -> void* {
        void* p = ws + off;
        off += (bytes + 255) & ~(size_t)255;
        return p;
    };
    // feature buffers have N+1 rows; row N is the zero row
    unsigned short* xb = (unsigned short*)alloc((size_t)(N + 1) * DH * 2);
    unsigned short* hA = (unsigned short*)alloc((size_t)(N + 1) * DH * 2);
    unsigned short* hB = (unsigned short*)alloc((size_t)(N + 1) * DH * 2);
    unsigned short* wt[8];
    for (int m = 0; m < 8; ++m) wt[m] = (unsigned short*)alloc(16384 * 2);
    int* cnt     = (int*)alloc((size_t)N * 4);
    int* rp_part = (int*)alloc((size_t)(N + 1) * 4);
    int* row_ptr = (int*)alloc((size_t)(N + 1) * 4);
    int* rank    = (int*)alloc((size_t)E * 4);
    int* bsum    = (int*)alloc(256 * 4);
    int* esrc    = (int*)alloc((size_t)Epad * 4);

    WPrep wp;
    wp.src[0] = (const float*)d_in[2];
    wp.src[1] = (const float*)d_in[4];
    wp.src[2] = (const float*)d_in[6];
    wp.src[3] = (const float*)d_in[8];
    wp.src[4] = (const float*)d_in[10];
    wp.src[5] = (const float*)d_in[12];
    wp.src[6] = (const float*)d_in[14];
    wp.src[7] = (const float*)d_in[16];
    for (int m = 0; m < 8; ++m) wp.dst[m] = wt[m];
    int n4 = N * DH / 4;
    int prep_items = n4 + N + 7 * 16384 + 8192 + 384 + Epad;
    prep_kernel<<<(prep_items + 255) / 256, 256, 0, stream>>>(
        x, xb, hA, hB, n4, wp, cnt, esrc, Epad, N);

    int nb = (N + 1 + 255) / 256;
    int eb = (E + 255) / 256;
    hist_kernel<<<eb, 256, 0, stream>>>(dstv, cnt, rank, E, N);
    scan1_kernel<<<nb, 256, 0, stream>>>(cnt, rp_part, bsum, N);
    scan2_kernel<<<1, 256, 0, stream>>>(bsum, nb);
    scan3_fill_kernel<<<eb, 256, 0, stream>>>(rp_part, bsum, row_ptr,
                                              src, dstv, rank, esrc, N, E);

    int gb = (N + 15) / 16;

    const float* c1b1 = (const float*)d_in[3];
    const float* c1b2 = (const float*)d_in[5];
    const float* c2b1 = (const float*)d_in[7];
    const float* c2b2 = (const float*)d_in[9];
    const float* c3b1 = (const float*)d_in[11];
    const float* c3b2 = (const float*)d_in[13];
    const float* l1b  = (const float*)d_in[15];
    const float* l2b  = (const float*)d_in[17];

    layer_kernel<false><<<gb, 256, 0, stream>>>(
        xb, row_ptr, esrc, wt[0], c1b1, wt[1], c1b2,
        nullptr, nullptr, nullptr, nullptr, hA, N);
    layer_kernel<false><<<gb, 256, 0, stream>>>(
        hA, row_ptr, esrc, wt[2], c2b1, wt[3], c2b2,
        nullptr, nullptr, nullptr, nullptr, hB, N);
    layer_kernel<true><<<gb, 256, 0, stream>>>(
        hB, row_ptr, esrc, wt[4], c3b1, wt[5], c3b2,
        wt[6], l1b, wt[7], l2b, d_out, N);
}